// Round 4
// baseline (1670.165 us; speedup 1.0000x reference)
//
#include <hip/hip_runtime.h>

#define NHW 15
#define NWIN (8 * NHW * NHW)  // 1800

typedef __bf16 bf16x8 __attribute__((ext_vector_type(8)));
typedef float f32x4 __attribute__((ext_vector_type(4)));
typedef unsigned short u16x8 __attribute__((ext_vector_type(8)));

__device__ __forceinline__ unsigned short f2bf(float f) {
  unsigned x = __float_as_uint(f);
  unsigned r = ((x >> 16) & 1u) + 0x7fffu;  // round-to-nearest-even
  x += r;
  return (unsigned short)(x >> 16);
}

// K-permutation for GEMM1: stored col c' <-> original channel c = 64*(c'%8) + c'/8.
// Applied to BOTH xv staging and w_qkv columns; dot product is invariant.
// w_qkv: dst[o][a*8+e] = wq[o][64*e + a].  w_out: unpermuted.
__global__ void convert_weights(const float* __restrict__ wq,
                                const float* __restrict__ wo,
                                unsigned short* __restrict__ dst) {
  int t = blockIdx.x * 256 + threadIdx.x;
  if (t < 98304) {  // 1536 * 64
    int o = t >> 6, a = t & 63;
    const float* src = wq + (size_t)o * 512 + a;
    u16x8 v;
    #pragma unroll
    for (int e = 0; e < 8; ++e) v[e] = f2bf(src[e * 64]);
    *(u16x8*)(dst + (size_t)o * 512 + a * 8) = v;
  } else {          // w_out: 512*512 / 4 per thread
    int i = (t - 98304) * 4;
    float4 v = *(const float4*)(wo + i);
    ushort4 o4;
    o4.x = f2bf(v.x); o4.y = f2bf(v.y); o4.z = f2bf(v.z); o4.w = f2bf(v.w);
    *(ushort4*)(dst + 786432 + i) = o4;
  }
}

// min-waves=2 -> VGPR cap 256: qp/kp/vp (96) + AGPR acc fit WITHOUT spilling.
// (512,4) in round 2 capped at 128 -> 12 GB of scratch spill traffic. Do not raise.
__launch_bounds__(512, 2)
__global__ void swin_kernel(const float* __restrict__ x,
                            const float* __restrict__ b_out,
                            const unsigned short* __restrict__ wq_all,  // [1536][512] bf16, K-permuted
                            const unsigned short* __restrict__ wo,      // [512][512]  bf16
                            float* __restrict__ res) {
  // single 80KiB region, time-shared:
  //   phase A: xv[64][520] bf16 (66560B), K-permuted cols: c' = pos*8 + e
  //   phase B: 8 x 10240B per-wave attention scratch
  //   phase C: att_out[64][520] bf16
  //   phase D: epilogue pixel-major f32 [32][517] (66176B)
  __shared__ __align__(16) unsigned short lds0[40960];  // 81920 B

  const int tid  = threadIdx.x;
  const int wave = tid >> 6;
  const int ln   = tid & 63;
  const int rowa = ln & 15;   // A-frag row / B-frag col within 16-tile
  const int kgrp = ln >> 4;   // 0..3 : k-subgroup (8 elems each)
  const int rbase = kgrp * 4; // C/D-layout row base within 16-tile

  const int bid = blockIdx.x;
  const int b  = bid / (NHW * NHW);
  const int rm = bid % (NHW * NHW);
  const int n  = rm / NHW;
  const int w  = rm % NHW;
  const int i0 = n * 4, j0 = w * 4;

  // ---------------- stage patch xv (bf16, K-permuted) ----------------
  // xv'[l][pos*8+e] = x[b, i0+pos/8, j0+pos%8, 8l+e]
  {
    const int l_st = ln;
    const int kj_st = wave;
    for (int r = 0; r < 8; ++r) {
      const float* src = x + (((size_t)(b * 64 + i0 + r)) * 64 + j0 + kj_st) * 512 + 8 * l_st;
      float4 v0 = *(const float4*)(src);
      float4 v1 = *(const float4*)(src + 4);
      u16x8 pk;
      pk[0] = f2bf(v0.x); pk[1] = f2bf(v0.y); pk[2] = f2bf(v0.z); pk[3] = f2bf(v0.w);
      pk[4] = f2bf(v1.x); pk[5] = f2bf(v1.y); pk[6] = f2bf(v1.z); pk[7] = f2bf(v1.w);
      *(u16x8*)(lds0 + l_st * 520 + (r * 8 + kj_st) * 8) = pk;
    }
  }
  __syncthreads();

  // ---------------- GEMM1: qkv = xv @ W^T (3 steps; wave owns head `wave`) ----
  unsigned qp[4][4][2], kp[4][4][2], vp[4][4][2];  // packed bf16 pairs (rows 2p,2p+1)
  {
    auto step = [&](int O, unsigned (&dst)[4][4][2]) {
      f32x4 acc[4][4];
      #pragma unroll
      for (int i = 0; i < 4; ++i)
        #pragma unroll
        for (int j = 0; j < 4; ++j) acc[i][j] = (f32x4){0.f, 0.f, 0.f, 0.f};
      for (int ks = 0; ks < 16; ++ks) {
        bf16x8 a[4];
        #pragma unroll
        for (int mt = 0; mt < 4; ++mt)
          a[mt] = *(const bf16x8*)(lds0 + (mt * 16 + rowa) * 520 + ks * 32 + kgrp * 8);
        #pragma unroll
        for (int nt = 0; nt < 4; ++nt) {
          bf16x8 bfr = *(const bf16x8*)(wq_all + (size_t)(O + nt * 16 + rowa) * 512 + ks * 32 + kgrp * 8);
          #pragma unroll
          for (int mt = 0; mt < 4; ++mt)
            acc[mt][nt] = __builtin_amdgcn_mfma_f32_16x16x32_bf16(a[mt], bfr, acc[mt][nt], 0, 0, 0);
        }
      }
      #pragma unroll
      for (int mt = 0; mt < 4; ++mt)
        #pragma unroll
        for (int nt = 0; nt < 4; ++nt)
          #pragma unroll
          for (int p = 0; p < 2; ++p)
            dst[mt][nt][p] = (unsigned)f2bf(acc[mt][nt][2 * p]) |
                             ((unsigned)f2bf(acc[mt][nt][2 * p + 1]) << 16);
    };
    step(wave * 64,        qp);
    step(512 + wave * 64,  kp);
    step(1024 + wave * 64, vp);
  }
  __syncthreads();  // xv dead; per-wave scratch may overlay lds0

  // ---------------- attention: head = wave, all private -------------
  unsigned short* qsc = lds0 + wave * 5120;  // 64 x 40 bf16 rows (80B, 16B aligned)
  unsigned short* ksc = qsc + 2560;

  f32x4 dt_[4][4];
  #pragma unroll
  for (int i = 0; i < 4; ++i)
    #pragma unroll
    for (int j = 0; j < 4; ++j) dt_[i][j] = (f32x4){0.f, 0.f, 0.f, 0.f};

  #pragma unroll
  for (int h2 = 0; h2 < 2; ++h2) {  // d-half of K=64
    #pragma unroll
    for (int mt = 0; mt < 4; ++mt)
      #pragma unroll
      for (int cc = 0; cc < 2; ++cc) {
        int ct = 2 * h2 + cc;
        #pragma unroll
        for (int p = 0; p < 2; ++p) {
          unsigned uq = qp[mt][ct][p];
          unsigned uk = kp[mt][ct][p];
          int rr = mt * 16 + rbase + 2 * p;
          int dd = cc * 16 + rowa;
          qsc[rr * 40 + dd]       = (unsigned short)uq;
          qsc[(rr + 1) * 40 + dd] = (unsigned short)(uq >> 16);
          ksc[rr * 40 + dd]       = (unsigned short)uk;
          ksc[(rr + 1) * 40 + dd] = (unsigned short)(uk >> 16);
        }
      }
    bf16x8 aq[4];
    #pragma unroll
    for (int mt = 0; mt < 4; ++mt)
      aq[mt] = *(const bf16x8*)(qsc + (mt * 16 + rowa) * 40 + kgrp * 8);
    #pragma unroll
    for (int nt = 0; nt < 4; ++nt) {
      bf16x8 bk = *(const bf16x8*)(ksc + (nt * 16 + rowa) * 40 + kgrp * 8);
      #pragma unroll
      for (int mt = 0; mt < 4; ++mt)
        dt_[mt][nt] = __builtin_amdgcn_mfma_f32_16x16x32_bf16(aq[mt], bk, dt_[mt][nt], 0, 0, 0);
    }
  }

  // softmax (scale = hd^-0.5 = 1/8); per-row constant bias drops out exactly
  const float SC = 0.125f * 1.44269504088896f;
  float rsum[4][4];
  #pragma unroll
  for (int mt = 0; mt < 4; ++mt)
    #pragma unroll
    for (int j = 0; j < 4; ++j) {
      float m = dt_[mt][0][j];
      #pragma unroll
      for (int nt = 1; nt < 4; ++nt) m = fmaxf(m, dt_[mt][nt][j]);
      #pragma unroll
      for (int s = 1; s < 16; s <<= 1) m = fmaxf(m, __shfl_xor(m, s, 64));
      float sum = 0.f;
      #pragma unroll
      for (int nt = 0; nt < 4; ++nt) {
        float p = exp2f((dt_[mt][nt][j] - m) * SC);
        dt_[mt][nt][j] = p;
        sum += p;
      }
      #pragma unroll
      for (int s = 1; s < 16; s <<= 1) sum += __shfl_xor(sum, s, 64);
      rsum[mt][j] = sum;
    }

  // PV: out_h = P @ v  (stage P and v^T per m-half; same-wave scratch reuse)
  unsigned short* Psc  = qsc;
  unsigned short* vTsc = ksc;
  f32x4 oat[4][4];
  #pragma unroll
  for (int i = 0; i < 4; ++i)
    #pragma unroll
    for (int j = 0; j < 4; ++j) oat[i][j] = (f32x4){0.f, 0.f, 0.f, 0.f};

  #pragma unroll
  for (int mh = 0; mh < 2; ++mh) {
    #pragma unroll
    for (int mt = 0; mt < 4; ++mt)
      #pragma unroll
      for (int cc = 0; cc < 2; ++cc) {
        int ct = 2 * mh + cc;
        #pragma unroll
        for (int j = 0; j < 4; ++j)
          Psc[(mt * 16 + rbase + j) * 40 + cc * 16 + rowa] = f2bf(dt_[mt][ct][j]);
      }
    #pragma unroll
    for (int mm = 0; mm < 2; ++mm) {
      int mtm = 2 * mh + mm;
      #pragma unroll
      for (int ct = 0; ct < 4; ++ct)
        #pragma unroll
        for (int p = 0; p < 2; ++p) {
          unsigned u = vp[mtm][ct][p];
          int m_ = mm * 16 + rbase + 2 * p;
          int d  = ct * 16 + rowa;
          *(unsigned*)(vTsc + d * 40 + m_) = u;  // two adjacent m' -> one b32 write
        }
    }
    bf16x8 ap[4];
    #pragma unroll
    for (int mt = 0; mt < 4; ++mt)
      ap[mt] = *(const bf16x8*)(Psc + (mt * 16 + rowa) * 40 + kgrp * 8);
    #pragma unroll
    for (int dtt = 0; dtt < 4; ++dtt) {
      bf16x8 bv = *(const bf16x8*)(vTsc + (dtt * 16 + rowa) * 40 + kgrp * 8);
      #pragma unroll
      for (int mt = 0; mt < 4; ++mt)
        oat[mt][dtt] = __builtin_amdgcn_mfma_f32_16x16x32_bf16(ap[mt], bv, oat[mt][dtt], 0, 0, 0);
    }
  }

  __syncthreads();  // all waves done with private scratch before att_out overlay

  // normalize + stage att_out (cols [wave*64, wave*64+64)) into lds0
  #pragma unroll
  for (int mt = 0; mt < 4; ++mt)
    #pragma unroll
    for (int j = 0; j < 4; ++j) {
      float inv = 1.f / rsum[mt][j];
      #pragma unroll
      for (int dtt = 0; dtt < 4; ++dtt)
        lds0[(mt * 16 + rbase + j) * 520 + wave * 64 + dtt * 16 + rowa] =
            f2bf(oat[mt][dtt][j] * inv);
    }
  __syncthreads();

  // ---------------- GEMM2: out2 = att_out @ w_out^T + b_out ----------
  f32x4 a2[4][4];
  #pragma unroll
  for (int i = 0; i < 4; ++i)
    #pragma unroll
    for (int j = 0; j < 4; ++j) a2[i][j] = (f32x4){0.f, 0.f, 0.f, 0.f};
  for (int ks = 0; ks < 16; ++ks) {
    bf16x8 a[4];
    #pragma unroll
    for (int mt = 0; mt < 4; ++mt)
      a[mt] = *(const bf16x8*)(lds0 + (mt * 16 + rowa) * 520 + ks * 32 + kgrp * 8);
    #pragma unroll
    for (int nt = 0; nt < 4; ++nt) {
      bf16x8 bw = *(const bf16x8*)(wo + (size_t)(wave * 64 + nt * 16 + rowa) * 512 + ks * 32 + kgrp * 8);
      #pragma unroll
      for (int mt = 0; mt < 4; ++mt)
        a2[mt][nt] = __builtin_amdgcn_mfma_f32_16x16x32_bf16(a[mt], bw, a2[mt][nt], 0, 0, 0);
    }
  }

  float bias[4];
  #pragma unroll
  for (int nt = 0; nt < 4; ++nt) bias[nt] = b_out[wave * 64 + nt * 16 + rowa];

  // ---------------- epilogue: LDS un-scramble + COALESCED atomic scatter ----
  // value (l = mt*16+kgrp*4+j, o = wave*64+nt*16+rowa):
  //   pixel p = o&63 = nt*16+rowa, channel ch = l*8 + (o>>6) = l*8 + wave.
  // Phase ph covers p in [32ph, 32ph+32): stage fl[p-32ph][ch] f32 (stride 517),
  // then wave-contiguous 1KB reads -> 4 consecutive-float atomicAdds per lane.
  __syncthreads();  // GEMM2's lds0 reads complete before overlay
  float* fl = (float*)lds0;  // [32][517] f32 = 66176 B
  #pragma unroll
  for (int ph = 0; ph < 2; ++ph) {
    if (ph) __syncthreads();  // phase-0 reads done before rewrite
    #pragma unroll
    for (int nt2 = 0; nt2 < 2; ++nt2) {
      int nt = 2 * ph + nt2;
      int prow = nt2 * 16 + rowa;
      #pragma unroll
      for (int mt = 0; mt < 4; ++mt)
        #pragma unroll
        for (int j = 0; j < 4; ++j) {
          int ch = (mt * 16 + rbase + j) * 8 + wave;
          fl[prow * 517 + ch] = a2[mt][nt][j] + bias[nt];
        }
    }
    __syncthreads();
    #pragma unroll
    for (int it = 0; it < 8; ++it) {
      int idx = it * 512 + tid;        // float4 index in [0,4096)
      int pp  = idx >> 7;              // local pixel 0..31
      int c4  = (idx & 127) << 2;      // channel 0..508
      float4 v = *(const float4*)(fl + pp * 517 + c4);
      int p  = ph * 32 + pp;
      int gh = i0 + (p >> 3), gw = j0 + (p & 7);
      float* dst = res + (((size_t)(b * 64 + gh)) * 64 + gw) * 512 + c4;
      atomicAdd(dst + 0, v.x);
      atomicAdd(dst + 1, v.y);
      atomicAdd(dst + 2, v.z);
      atomicAdd(dst + 3, v.w);
    }
  }
}

extern "C" void kernel_launch(void* const* d_in, const int* in_sizes, int n_in,
                              void* d_out, int out_size, void* d_ws, size_t ws_size,
                              hipStream_t stream) {
  const float* x      = (const float*)d_in[0];
  const float* w_qkv  = (const float*)d_in[1];
  const float* w_out  = (const float*)d_in[2];
  const float* b_out  = (const float*)d_in[3];
  // d_in[4], d_in[5] (rel_h, rel_w): per-query-row constant bias is softmax-invariant -> unused
  float* res = (float*)d_out;
  unsigned short* wbf = (unsigned short*)d_ws;  // [0,2MB) weights bf16

  hipMemsetAsync(d_out, 0, (size_t)out_size * sizeof(float), stream);
  convert_weights<<<640, 256, 0, stream>>>(w_qkv, w_out, wbf);
  swin_kernel<<<NWIN, 512, 0, stream>>>(x, b_out, wbf, wbf + 786432, res);
}

// Round 5
// 1060.329 us; speedup vs baseline: 1.5751x; 1.5751x over previous
//
#include <hip/hip_runtime.h>

#define NHW 15

typedef __bf16 bf16x8 __attribute__((ext_vector_type(8)));
typedef float f32x4 __attribute__((ext_vector_type(4)));
typedef unsigned short u16x8 __attribute__((ext_vector_type(8)));

__device__ __forceinline__ unsigned short f2bf(float f) {
  unsigned x = __float_as_uint(f);
  unsigned r = ((x >> 16) & 1u) + 0x7fffu;  // round-to-nearest-even
  x += r;
  return (unsigned short)(x >> 16);
}

// K-permutation for GEMM1: stored col c' <-> original channel c = 64*(c'%8) + c'/8.
// Applied to BOTH xv staging and w_qkv columns; dot product is invariant.
// w_qkv: dst[o][a*8+e] = wq[o][64*e + a].  w_out: unpermuted.
__global__ void convert_weights(const float* __restrict__ wq,
                                const float* __restrict__ wo,
                                unsigned short* __restrict__ dst) {
  int t = blockIdx.x * 256 + threadIdx.x;
  if (t < 98304) {  // 1536 * 64
    int o = t >> 6, a = t & 63;
    const float* src = wq + (size_t)o * 512 + a;
    u16x8 v;
    #pragma unroll
    for (int e = 0; e < 8; ++e) v[e] = f2bf(src[e * 64]);
    *(u16x8*)(dst + (size_t)o * 512 + a * 8) = v;
  } else {          // w_out: 512*512 / 4 per thread
    int i = (t - 98304) * 4;
    float4 v = *(const float4*)(wo + i);
    ushort4 o4;
    o4.x = f2bf(v.x); o4.y = f2bf(v.y); o4.z = f2bf(v.z); o4.w = f2bf(v.w);
    *(ushort4*)(dst + 786432 + i) = o4;
  }
}

// min-waves=2 -> VGPR cap 256: qp/kp/vp (96) + AGPR acc fit WITHOUT spilling.
// (512,4) in round 2 capped at 128 -> 12 GB of scratch spill traffic. Do not raise.
//
// Parity-class launch: windows with fixed (n%2, w%2) never overlap (stride 4,
// kernel 8 -> same-parity windows are 8 apart >= kernel). 4 sequential launches;
// class (0,0) covers every output pixel exactly once -> plain stores (do_add=0);
// others load-add-store non-atomically (disjoint 2KB pixel runs within a launch).
__launch_bounds__(512, 2)
__global__ void swin_kernel(const float* __restrict__ x,
                            const float* __restrict__ b_out,
                            const unsigned short* __restrict__ wq_all,  // [1536][512] bf16, K-permuted
                            const unsigned short* __restrict__ wo,      // [512][512]  bf16
                            float* __restrict__ res,
                            int n0, int w0, int nN, int nW, int do_add) {
  // single 80KiB region, time-shared:
  //   phase A: xv[64][520] bf16 (66560B), K-permuted cols: c' = pos*8 + e
  //   phase B: 8 x 10240B per-wave attention scratch
  //   phase C: att_out[64][520] bf16
  //   phase D: epilogue pixel-major f32 [32][517] (66176B)
  __shared__ __align__(16) unsigned short lds0[40960];  // 81920 B

  const int tid  = threadIdx.x;
  const int wave = tid >> 6;
  const int ln   = tid & 63;
  const int rowa = ln & 15;   // A-frag row / B-frag col within 16-tile
  const int kgrp = ln >> 4;   // 0..3 : k-subgroup (8 elems each)
  const int rbase = kgrp * 4; // C/D-layout row base within 16-tile

  const int bid = blockIdx.x;
  const int b  = bid / (nN * nW);
  const int rm = bid % (nN * nW);
  const int n  = n0 + 2 * (rm / nW);
  const int w  = w0 + 2 * (rm % nW);
  const int i0 = n * 4, j0 = w * 4;

  // ---------------- stage patch xv (bf16, K-permuted) ----------------
  // xv'[l][pos*8+e] = x[b, i0+pos/8, j0+pos%8, 8l+e]
  {
    const int l_st = ln;
    const int kj_st = wave;
    for (int r = 0; r < 8; ++r) {
      const float* src = x + (((size_t)(b * 64 + i0 + r)) * 64 + j0 + kj_st) * 512 + 8 * l_st;
      float4 v0 = *(const float4*)(src);
      float4 v1 = *(const float4*)(src + 4);
      u16x8 pk;
      pk[0] = f2bf(v0.x); pk[1] = f2bf(v0.y); pk[2] = f2bf(v0.z); pk[3] = f2bf(v0.w);
      pk[4] = f2bf(v1.x); pk[5] = f2bf(v1.y); pk[6] = f2bf(v1.z); pk[7] = f2bf(v1.w);
      *(u16x8*)(lds0 + l_st * 520 + (r * 8 + kj_st) * 8) = pk;
    }
  }
  __syncthreads();

  // ---------------- GEMM1: qkv = xv @ W^T (3 steps; wave owns head `wave`) ----
  unsigned qp[4][4][2], kp[4][4][2], vp[4][4][2];  // packed bf16 pairs (rows 2p,2p+1)
  {
    auto step = [&](int O, unsigned (&dst)[4][4][2]) {
      f32x4 acc[4][4];
      #pragma unroll
      for (int i = 0; i < 4; ++i)
        #pragma unroll
        for (int j = 0; j < 4; ++j) acc[i][j] = (f32x4){0.f, 0.f, 0.f, 0.f};
      for (int ks = 0; ks < 16; ++ks) {
        bf16x8 a[4];
        #pragma unroll
        for (int mt = 0; mt < 4; ++mt)
          a[mt] = *(const bf16x8*)(lds0 + (mt * 16 + rowa) * 520 + ks * 32 + kgrp * 8);
        #pragma unroll
        for (int nt = 0; nt < 4; ++nt) {
          bf16x8 bfr = *(const bf16x8*)(wq_all + (size_t)(O + nt * 16 + rowa) * 512 + ks * 32 + kgrp * 8);
          #pragma unroll
          for (int mt = 0; mt < 4; ++mt)
            acc[mt][nt] = __builtin_amdgcn_mfma_f32_16x16x32_bf16(a[mt], bfr, acc[mt][nt], 0, 0, 0);
        }
      }
      #pragma unroll
      for (int mt = 0; mt < 4; ++mt)
        #pragma unroll
        for (int nt = 0; nt < 4; ++nt)
          #pragma unroll
          for (int p = 0; p < 2; ++p)
            dst[mt][nt][p] = (unsigned)f2bf(acc[mt][nt][2 * p]) |
                             ((unsigned)f2bf(acc[mt][nt][2 * p + 1]) << 16);
    };
    step(wave * 64,        qp);
    step(512 + wave * 64,  kp);
    step(1024 + wave * 64, vp);
  }
  __syncthreads();  // xv dead; per-wave scratch may overlay lds0

  // ---------------- attention: head = wave, all private -------------
  unsigned short* qsc = lds0 + wave * 5120;  // 64 x 40 bf16 rows (80B, 16B aligned)
  unsigned short* ksc = qsc + 2560;

  f32x4 dt_[4][4];
  #pragma unroll
  for (int i = 0; i < 4; ++i)
    #pragma unroll
    for (int j = 0; j < 4; ++j) dt_[i][j] = (f32x4){0.f, 0.f, 0.f, 0.f};

  #pragma unroll
  for (int h2 = 0; h2 < 2; ++h2) {  // d-half of K=64
    #pragma unroll
    for (int mt = 0; mt < 4; ++mt)
      #pragma unroll
      for (int cc = 0; cc < 2; ++cc) {
        int ct = 2 * h2 + cc;
        #pragma unroll
        for (int p = 0; p < 2; ++p) {
          unsigned uq = qp[mt][ct][p];
          unsigned uk = kp[mt][ct][p];
          int rr = mt * 16 + rbase + 2 * p;
          int dd = cc * 16 + rowa;
          qsc[rr * 40 + dd]       = (unsigned short)uq;
          qsc[(rr + 1) * 40 + dd] = (unsigned short)(uq >> 16);
          ksc[rr * 40 + dd]       = (unsigned short)uk;
          ksc[(rr + 1) * 40 + dd] = (unsigned short)(uk >> 16);
        }
      }
    bf16x8 aq[4];
    #pragma unroll
    for (int mt = 0; mt < 4; ++mt)
      aq[mt] = *(const bf16x8*)(qsc + (mt * 16 + rowa) * 40 + kgrp * 8);
    #pragma unroll
    for (int nt = 0; nt < 4; ++nt) {
      bf16x8 bk = *(const bf16x8*)(ksc + (nt * 16 + rowa) * 40 + kgrp * 8);
      #pragma unroll
      for (int mt = 0; mt < 4; ++mt)
        dt_[mt][nt] = __builtin_amdgcn_mfma_f32_16x16x32_bf16(aq[mt], bk, dt_[mt][nt], 0, 0, 0);
    }
  }

  // softmax (scale = hd^-0.5 = 1/8); per-row constant bias drops out exactly
  const float SC = 0.125f * 1.44269504088896f;
  float rsum[4][4];
  #pragma unroll
  for (int mt = 0; mt < 4; ++mt)
    #pragma unroll
    for (int j = 0; j < 4; ++j) {
      float m = dt_[mt][0][j];
      #pragma unroll
      for (int nt = 1; nt < 4; ++nt) m = fmaxf(m, dt_[mt][nt][j]);
      #pragma unroll
      for (int s = 1; s < 16; s <<= 1) m = fmaxf(m, __shfl_xor(m, s, 64));
      float sum = 0.f;
      #pragma unroll
      for (int nt = 0; nt < 4; ++nt) {
        float p = exp2f((dt_[mt][nt][j] - m) * SC);
        dt_[mt][nt][j] = p;
        sum += p;
      }
      #pragma unroll
      for (int s = 1; s < 16; s <<= 1) sum += __shfl_xor(sum, s, 64);
      rsum[mt][j] = sum;
    }

  // PV: out_h = P @ v  (stage P and v^T per m-half; same-wave scratch reuse)
  unsigned short* Psc  = qsc;
  unsigned short* vTsc = ksc;
  f32x4 oat[4][4];
  #pragma unroll
  for (int i = 0; i < 4; ++i)
    #pragma unroll
    for (int j = 0; j < 4; ++j) oat[i][j] = (f32x4){0.f, 0.f, 0.f, 0.f};

  #pragma unroll
  for (int mh = 0; mh < 2; ++mh) {
    #pragma unroll
    for (int mt = 0; mt < 4; ++mt)
      #pragma unroll
      for (int cc = 0; cc < 2; ++cc) {
        int ct = 2 * mh + cc;
        #pragma unroll
        for (int j = 0; j < 4; ++j)
          Psc[(mt * 16 + rbase + j) * 40 + cc * 16 + rowa] = f2bf(dt_[mt][ct][j]);
      }
    #pragma unroll
    for (int mm = 0; mm < 2; ++mm) {
      int mtm = 2 * mh + mm;
      #pragma unroll
      for (int ct = 0; ct < 4; ++ct)
        #pragma unroll
        for (int p = 0; p < 2; ++p) {
          unsigned u = vp[mtm][ct][p];
          int m_ = mm * 16 + rbase + 2 * p;
          int d  = ct * 16 + rowa;
          *(unsigned*)(vTsc + d * 40 + m_) = u;  // two adjacent m' -> one b32 write
        }
    }
    bf16x8 ap[4];
    #pragma unroll
    for (int mt = 0; mt < 4; ++mt)
      ap[mt] = *(const bf16x8*)(Psc + (mt * 16 + rowa) * 40 + kgrp * 8);
    #pragma unroll
    for (int dtt = 0; dtt < 4; ++dtt) {
      bf16x8 bv = *(const bf16x8*)(vTsc + (dtt * 16 + rowa) * 40 + kgrp * 8);
      #pragma unroll
      for (int mt = 0; mt < 4; ++mt)
        oat[mt][dtt] = __builtin_amdgcn_mfma_f32_16x16x32_bf16(ap[mt], bv, oat[mt][dtt], 0, 0, 0);
    }
  }

  __syncthreads();  // all waves done with private scratch before att_out overlay

  // normalize + stage att_out (cols [wave*64, wave*64+64)) into lds0
  #pragma unroll
  for (int mt = 0; mt < 4; ++mt)
    #pragma unroll
    for (int j = 0; j < 4; ++j) {
      float inv = 1.f / rsum[mt][j];
      #pragma unroll
      for (int dtt = 0; dtt < 4; ++dtt)
        lds0[(mt * 16 + rbase + j) * 520 + wave * 64 + dtt * 16 + rowa] =
            f2bf(oat[mt][dtt][j] * inv);
    }
  __syncthreads();

  // ---------------- GEMM2: out2 = att_out @ w_out^T + b_out ----------
  f32x4 a2[4][4];
  #pragma unroll
  for (int i = 0; i < 4; ++i)
    #pragma unroll
    for (int j = 0; j < 4; ++j) a2[i][j] = (f32x4){0.f, 0.f, 0.f, 0.f};
  for (int ks = 0; ks < 16; ++ks) {
    bf16x8 a[4];
    #pragma unroll
    for (int mt = 0; mt < 4; ++mt)
      a[mt] = *(const bf16x8*)(lds0 + (mt * 16 + rowa) * 520 + ks * 32 + kgrp * 8);
    #pragma unroll
    for (int nt = 0; nt < 4; ++nt) {
      bf16x8 bw = *(const bf16x8*)(wo + (size_t)(wave * 64 + nt * 16 + rowa) * 512 + ks * 32 + kgrp * 8);
      #pragma unroll
      for (int mt = 0; mt < 4; ++mt)
        a2[mt][nt] = __builtin_amdgcn_mfma_f32_16x16x32_bf16(a[mt], bw, a2[mt][nt], 0, 0, 0);
    }
  }

  float bias[4];
  #pragma unroll
  for (int nt = 0; nt < 4; ++nt) bias[nt] = b_out[wave * 64 + nt * 16 + rowa];

  // ---------------- epilogue: LDS un-scramble + NON-ATOMIC write ----
  // value (l = mt*16+kgrp*4+j, o = wave*64+nt*16+rowa):
  //   pixel p = nt*16+rowa, channel ch = l*8 + wave.
  // Phase ph covers p in [32ph, 32ph+32): stage fl[p-32ph][ch] f32 (stride 517),
  // then wave-contiguous 1KB reads -> float4 store (or load-add-store).
  __syncthreads();  // GEMM2's lds0 reads complete before overlay
  float* fl = (float*)lds0;  // [32][517] f32 = 66176 B
  #pragma unroll
  for (int ph = 0; ph < 2; ++ph) {
    if (ph) __syncthreads();  // phase-0 reads done before rewrite
    #pragma unroll
    for (int nt2 = 0; nt2 < 2; ++nt2) {
      int nt = 2 * ph + nt2;
      int prow = nt2 * 16 + rowa;
      #pragma unroll
      for (int mt = 0; mt < 4; ++mt)
        #pragma unroll
        for (int j = 0; j < 4; ++j) {
          int ch = (mt * 16 + rbase + j) * 8 + wave;
          fl[prow * 517 + ch] = a2[mt][nt][j] + bias[nt];
        }
    }
    __syncthreads();
    #pragma unroll
    for (int it = 0; it < 8; ++it) {
      int idx = it * 512 + tid;        // float4 index in [0,4096)
      int pp  = idx >> 7;              // local pixel 0..31
      int c4  = (idx & 127) << 2;      // channel 0..508
      float4 v = *(const float4*)(fl + pp * 517 + c4);
      int p  = ph * 32 + pp;
      int gh = i0 + (p >> 3), gw = j0 + (p & 7);
      float* dst = res + (((size_t)(b * 64 + gh)) * 64 + gw) * 512 + c4;
      if (do_add) {
        float4 old = *(const float4*)dst;
        v.x += old.x; v.y += old.y; v.z += old.z; v.w += old.w;
      }
      *(float4*)dst = v;
    }
  }
}

extern "C" void kernel_launch(void* const* d_in, const int* in_sizes, int n_in,
                              void* d_out, int out_size, void* d_ws, size_t ws_size,
                              hipStream_t stream) {
  const float* x      = (const float*)d_in[0];
  const float* w_qkv  = (const float*)d_in[1];
  const float* w_out  = (const float*)d_in[2];
  const float* b_out  = (const float*)d_in[3];
  // d_in[4], d_in[5] (rel_h, rel_w): per-query-row constant bias is softmax-invariant -> unused
  float* res = (float*)d_out;
  unsigned short* wbf = (unsigned short*)d_ws;  // [0,2MB) weights bf16

  convert_weights<<<640, 256, 0, stream>>>(w_qkv, w_out, wbf);

  // 4 parity classes; class (0,0) first with plain stores (covers every output
  // element exactly once -> no memset needed), remaining classes accumulate.
  const int cls[4][5] = {
      {0, 0, 8, 8, 0},  // n even, w even: 512 blocks, store
      {0, 1, 8, 7, 1},  // n even, w odd : 448 blocks, add
      {1, 0, 7, 8, 1},  // n odd,  w even: 448 blocks, add
      {1, 1, 7, 7, 1},  // n odd,  w odd : 392 blocks, add
  };
  for (int c = 0; c < 4; ++c) {
    int nblk = 8 * cls[c][2] * cls[c][3];
    swin_kernel<<<nblk, 512, 0, stream>>>(x, b_out, wbf, wbf + 786432, res,
                                          cls[c][0], cls[c][1], cls[c][2],
                                          cls[c][3], cls[c][4]);
  }
}

// Round 6
// 645.113 us; speedup vs baseline: 2.5889x; 1.6436x over previous
//
#include <hip/hip_runtime.h>

#define NHW 15

typedef __bf16 bf16x8 __attribute__((ext_vector_type(8)));
typedef float f32x4 __attribute__((ext_vector_type(4)));
typedef unsigned short u16x8 __attribute__((ext_vector_type(8)));

__device__ __forceinline__ unsigned short f2bf(float f) {
  unsigned x = __float_as_uint(f);
  unsigned r = ((x >> 16) & 1u) + 0x7fffu;  // round-to-nearest-even
  x += r;
  return (unsigned short)(x >> 16);
}

// K-permutation for GEMM1: stored col c' <-> original channel c = 64*(c'%8) + c'/8.
// Applied to BOTH xv staging and w_qkv columns; dot product is invariant.
// w_qkv: dst[o][a*8+e] = wq[o][64*e + a].  w_out: unpermuted.
__global__ void convert_weights(const float* __restrict__ wq,
                                const float* __restrict__ wo,
                                unsigned short* __restrict__ dst) {
  int t = blockIdx.x * 256 + threadIdx.x;
  if (t < 98304) {  // 1536 * 64
    int o = t >> 6, a = t & 63;
    const float* src = wq + (size_t)o * 512 + a;
    u16x8 v;
    #pragma unroll
    for (int e = 0; e < 8; ++e) v[e] = f2bf(src[e * 64]);
    *(u16x8*)(dst + (size_t)o * 512 + a * 8) = v;
  } else {          // w_out: 512*512 / 4 per thread
    int i = (t - 98304) * 4;
    float4 v = *(const float4*)(wo + i);
    ushort4 o4;
    o4.x = f2bf(v.x); o4.y = f2bf(v.y); o4.z = f2bf(v.z); o4.w = f2bf(v.w);
    *(ushort4*)(dst + 786432 + i) = o4;
  }
}

// __launch_bounds__(512) -> VGPR cap 256 (8 waves/block needs 2/SIMD).
// Live peak ~190 regs (qp/kp/vp 96 + dt_ 64 + frags) -> fits, NO spills.
// Round-2's (512,4) capped at 128 -> 12GB spill traffic; round-5's (512,2)
// also spilled (582MB writes/launch). Do not add a min-waves argument.
//
// Parity-class launch: windows with fixed (n%2, w%2) never overlap (stride 4,
// kernel 8). 4 sequential launches; class (0,0) covers every output pixel
// exactly once -> plain stores (do_add=0); others load-add-store.
__launch_bounds__(512)
__global__ void swin_kernel(const float* __restrict__ x,
                            const float* __restrict__ b_out,
                            const unsigned short* __restrict__ wq_all,  // [1536][512] bf16, K-permuted
                            const unsigned short* __restrict__ wo,      // [512][512]  bf16
                            float* __restrict__ res,
                            int n0, int w0, int nN, int nW, int do_add) {
  // 1 block/CU -> use the full 160KB LDS: two SEPARATE regions (no overlay
  // between xv and attention scratch -> one fewer barrier, simpler lifetimes).
  //   region xv : xv[64][520] bf16 (66560B); later att_out[64][520]
  //   region sc : 8 x 10240B per-wave attention scratch; later fl[32][517] f32
  __shared__ __align__(16) unsigned short lds_xv[64 * 520];  // 66560 B
  __shared__ __align__(16) unsigned short lds_sc[8 * 5120];  // 81920 B

  const int tid  = threadIdx.x;
  const int wave = tid >> 6;
  const int ln   = tid & 63;
  const int rowa = ln & 15;   // A-frag row / B-frag col within 16-tile
  const int kgrp = ln >> 4;   // 0..3 : k-subgroup (8 elems each)
  const int rbase = kgrp * 4; // C/D-layout row base within 16-tile

  const int bid = blockIdx.x;
  const int b  = bid / (nN * nW);
  const int rm = bid % (nN * nW);
  const int n  = n0 + 2 * (rm / nW);
  const int w  = w0 + 2 * (rm % nW);
  const int i0 = n * 4, j0 = w * 4;

  // ---------------- stage patch xv (bf16, K-permuted) ----------------
  // xv'[l][pos*8+e] = x[b, i0+pos/8, j0+pos%8, 8l+e]
  // Prefetch ALL 16 float4 loads first (one HBM latency), then pack+write.
  {
    const float* src = x + (((size_t)(b * 64 + i0)) * 64 + j0 + wave) * 512 + 8 * ln;
    float4 v0[8], v1[8];
    #pragma unroll
    for (int r = 0; r < 8; ++r) {
      v0[r] = *(const float4*)(src + (size_t)r * 32768);      // row stride 64*512
      v1[r] = *(const float4*)(src + (size_t)r * 32768 + 4);
    }
    #pragma unroll
    for (int r = 0; r < 8; ++r) {
      u16x8 pk;
      pk[0] = f2bf(v0[r].x); pk[1] = f2bf(v0[r].y); pk[2] = f2bf(v0[r].z); pk[3] = f2bf(v0[r].w);
      pk[4] = f2bf(v1[r].x); pk[5] = f2bf(v1[r].y); pk[6] = f2bf(v1[r].z); pk[7] = f2bf(v1[r].w);
      *(u16x8*)(lds_xv + ln * 520 + (r * 8 + wave) * 8) = pk;
    }
  }
  __syncthreads();

  // ---------------- GEMM1: qkv = xv @ W^T (3 steps; wave owns head `wave`) ----
  unsigned qp[4][4][2], kp[4][4][2], vp[4][4][2];  // packed bf16 pairs (rows 2p,2p+1)
  {
    auto step = [&](int O, unsigned (&dst)[4][4][2]) {
      f32x4 acc[4][4];
      #pragma unroll
      for (int i = 0; i < 4; ++i)
        #pragma unroll
        for (int j = 0; j < 4; ++j) acc[i][j] = (f32x4){0.f, 0.f, 0.f, 0.f};
      #pragma unroll 2
      for (int ks = 0; ks < 16; ++ks) {
        bf16x8 a[4];
        #pragma unroll
        for (int mt = 0; mt < 4; ++mt)
          a[mt] = *(const bf16x8*)(lds_xv + (mt * 16 + rowa) * 520 + ks * 32 + kgrp * 8);
        #pragma unroll
        for (int nt = 0; nt < 4; ++nt) {
          bf16x8 bfr = *(const bf16x8*)(wq_all + (size_t)(O + nt * 16 + rowa) * 512 + ks * 32 + kgrp * 8);
          #pragma unroll
          for (int mt = 0; mt < 4; ++mt)
            acc[mt][nt] = __builtin_amdgcn_mfma_f32_16x16x32_bf16(a[mt], bfr, acc[mt][nt], 0, 0, 0);
        }
      }
      #pragma unroll
      for (int mt = 0; mt < 4; ++mt)
        #pragma unroll
        for (int nt = 0; nt < 4; ++nt)
          #pragma unroll
          for (int p = 0; p < 2; ++p)
            dst[mt][nt][p] = (unsigned)f2bf(acc[mt][nt][2 * p]) |
                             ((unsigned)f2bf(acc[mt][nt][2 * p + 1]) << 16);
    };
    step(wave * 64,        qp);
    step(512 + wave * 64,  kp);
    step(1024 + wave * 64, vp);
  }
  // no barrier: attention scratch is a separate LDS region, wave-private.

  // ---------------- attention: head = wave, all private -------------
  unsigned short* qsc = lds_sc + wave * 5120;  // 64 x 40 bf16 rows (80B, 16B aligned)
  unsigned short* ksc = qsc + 2560;

  f32x4 dt_[4][4];
  #pragma unroll
  for (int i = 0; i < 4; ++i)
    #pragma unroll
    for (int j = 0; j < 4; ++j) dt_[i][j] = (f32x4){0.f, 0.f, 0.f, 0.f};

  #pragma unroll
  for (int h2 = 0; h2 < 2; ++h2) {  // d-half of K=64
    #pragma unroll
    for (int mt = 0; mt < 4; ++mt)
      #pragma unroll
      for (int cc = 0; cc < 2; ++cc) {
        int ct = 2 * h2 + cc;
        #pragma unroll
        for (int p = 0; p < 2; ++p) {
          unsigned uq = qp[mt][ct][p];
          unsigned uk = kp[mt][ct][p];
          int rr = mt * 16 + rbase + 2 * p;
          int dd = cc * 16 + rowa;
          qsc[rr * 40 + dd]       = (unsigned short)uq;
          qsc[(rr + 1) * 40 + dd] = (unsigned short)(uq >> 16);
          ksc[rr * 40 + dd]       = (unsigned short)uk;
          ksc[(rr + 1) * 40 + dd] = (unsigned short)(uk >> 16);
        }
      }
    bf16x8 aq[4];
    #pragma unroll
    for (int mt = 0; mt < 4; ++mt)
      aq[mt] = *(const bf16x8*)(qsc + (mt * 16 + rowa) * 40 + kgrp * 8);
    #pragma unroll
    for (int nt = 0; nt < 4; ++nt) {
      bf16x8 bk = *(const bf16x8*)(ksc + (nt * 16 + rowa) * 40 + kgrp * 8);
      #pragma unroll
      for (int mt = 0; mt < 4; ++mt)
        dt_[mt][nt] = __builtin_amdgcn_mfma_f32_16x16x32_bf16(aq[mt], bk, dt_[mt][nt], 0, 0, 0);
    }
  }

  // softmax (scale = hd^-0.5 = 1/8); per-row constant bias drops out exactly
  const float SC = 0.125f * 1.44269504088896f;
  float rsum[4][4];
  #pragma unroll
  for (int mt = 0; mt < 4; ++mt)
    #pragma unroll
    for (int j = 0; j < 4; ++j) {
      float m = dt_[mt][0][j];
      #pragma unroll
      for (int nt = 1; nt < 4; ++nt) m = fmaxf(m, dt_[mt][nt][j]);
      #pragma unroll
      for (int s = 1; s < 16; s <<= 1) m = fmaxf(m, __shfl_xor(m, s, 64));
      float sum = 0.f;
      #pragma unroll
      for (int nt = 0; nt < 4; ++nt) {
        float p = exp2f((dt_[mt][nt][j] - m) * SC);
        dt_[mt][nt][j] = p;
        sum += p;
      }
      #pragma unroll
      for (int s = 1; s < 16; s <<= 1) sum += __shfl_xor(sum, s, 64);
      rsum[mt][j] = sum;
    }

  // PV: out_h = P @ v  (stage P and v^T per m-half; same-wave scratch reuse)
  unsigned short* Psc  = qsc;
  unsigned short* vTsc = ksc;
  f32x4 oat[4][4];
  #pragma unroll
  for (int i = 0; i < 4; ++i)
    #pragma unroll
    for (int j = 0; j < 4; ++j) oat[i][j] = (f32x4){0.f, 0.f, 0.f, 0.f};

  #pragma unroll
  for (int mh = 0; mh < 2; ++mh) {
    #pragma unroll
    for (int mt = 0; mt < 4; ++mt)
      #pragma unroll
      for (int cc = 0; cc < 2; ++cc) {
        int ct = 2 * mh + cc;
        #pragma unroll
        for (int j = 0; j < 4; ++j)
          Psc[(mt * 16 + rbase + j) * 40 + cc * 16 + rowa] = f2bf(dt_[mt][ct][j]);
      }
    #pragma unroll
    for (int mm = 0; mm < 2; ++mm) {
      int mtm = 2 * mh + mm;
      #pragma unroll
      for (int ct = 0; ct < 4; ++ct)
        #pragma unroll
        for (int p = 0; p < 2; ++p) {
          unsigned u = vp[mtm][ct][p];
          int m_ = mm * 16 + rbase + 2 * p;
          int d  = ct * 16 + rowa;
          *(unsigned*)(vTsc + d * 40 + m_) = u;  // two adjacent m' -> one b32 write
        }
    }
    bf16x8 ap[4];
    #pragma unroll
    for (int mt = 0; mt < 4; ++mt)
      ap[mt] = *(const bf16x8*)(Psc + (mt * 16 + rowa) * 40 + kgrp * 8);
    #pragma unroll
    for (int dtt = 0; dtt < 4; ++dtt) {
      bf16x8 bv = *(const bf16x8*)(vTsc + (dtt * 16 + rowa) * 40 + kgrp * 8);
      #pragma unroll
      for (int mt = 0; mt < 4; ++mt)
        oat[mt][dtt] = __builtin_amdgcn_mfma_f32_16x16x32_bf16(ap[mt], bv, oat[mt][dtt], 0, 0, 0);
    }
  }

  __syncthreads();  // all waves done with GEMM1's xv reads before att_out overlay

  // normalize + stage att_out (cols [wave*64, wave*64+64)) into lds_xv
  #pragma unroll
  for (int mt = 0; mt < 4; ++mt)
    #pragma unroll
    for (int j = 0; j < 4; ++j) {
      float inv = 1.f / rsum[mt][j];
      #pragma unroll
      for (int dtt = 0; dtt < 4; ++dtt)
        lds_xv[(mt * 16 + rbase + j) * 520 + wave * 64 + dtt * 16 + rowa] =
            f2bf(oat[mt][dtt][j] * inv);
    }
  __syncthreads();

  // ---------------- GEMM2: out2 = att_out @ w_out^T + b_out ----------
  f32x4 a2[4][4];
  #pragma unroll
  for (int i = 0; i < 4; ++i)
    #pragma unroll
    for (int j = 0; j < 4; ++j) a2[i][j] = (f32x4){0.f, 0.f, 0.f, 0.f};
  #pragma unroll 2
  for (int ks = 0; ks < 16; ++ks) {
    bf16x8 a[4];
    #pragma unroll
    for (int mt = 0; mt < 4; ++mt)
      a[mt] = *(const bf16x8*)(lds_xv + (mt * 16 + rowa) * 520 + ks * 32 + kgrp * 8);
    #pragma unroll
    for (int nt = 0; nt < 4; ++nt) {
      bf16x8 bw = *(const bf16x8*)(wo + (size_t)(wave * 64 + nt * 16 + rowa) * 512 + ks * 32 + kgrp * 8);
      #pragma unroll
      for (int mt = 0; mt < 4; ++mt)
        a2[mt][nt] = __builtin_amdgcn_mfma_f32_16x16x32_bf16(a[mt], bw, a2[mt][nt], 0, 0, 0);
    }
  }

  float bias[4];
  #pragma unroll
  for (int nt = 0; nt < 4; ++nt) bias[nt] = b_out[wave * 64 + nt * 16 + rowa];

  // ---------------- epilogue: LDS un-scramble + NON-ATOMIC write ----
  // value (l = mt*16+kgrp*4+j, o = wave*64+nt*16+rowa):
  //   pixel p = nt*16+rowa, channel ch = l*8 + wave.
  // Phase ph covers p in [32ph, 32ph+32): stage fl[p-32ph][ch] f32 (stride 517)
  // in the (dead) scratch region, then wave-contiguous 1KB reads ->
  // float4 store (or load-add-store).
  float* fl = (float*)lds_sc;  // [32][517] f32 = 66176 B
  #pragma unroll
  for (int ph = 0; ph < 2; ++ph) {
    if (ph) __syncthreads();  // phase-0 reads done before rewrite
    #pragma unroll
    for (int nt2 = 0; nt2 < 2; ++nt2) {
      int nt = 2 * ph + nt2;
      int prow = nt2 * 16 + rowa;
      #pragma unroll
      for (int mt = 0; mt < 4; ++mt)
        #pragma unroll
        for (int j = 0; j < 4; ++j) {
          int ch = (mt * 16 + rbase + j) * 8 + wave;
          fl[prow * 517 + ch] = a2[mt][nt][j] + bias[nt];
        }
    }
    __syncthreads();
    #pragma unroll
    for (int it = 0; it < 8; ++it) {
      int idx = it * 512 + tid;        // float4 index in [0,4096)
      int pp  = idx >> 7;              // local pixel 0..31
      int c4  = (idx & 127) << 2;      // channel 0..508
      float4 v = *(const float4*)(fl + pp * 517 + c4);
      int p  = ph * 32 + pp;
      int gh = i0 + (p >> 3), gw = j0 + (p & 7);
      float* dst = res + (((size_t)(b * 64 + gh)) * 64 + gw) * 512 + c4;
      if (do_add) {
        float4 old = *(const float4*)dst;
        v.x += old.x; v.y += old.y; v.z += old.z; v.w += old.w;
      }
      *(float4*)dst = v;
    }
  }
}

extern "C" void kernel_launch(void* const* d_in, const int* in_sizes, int n_in,
                              void* d_out, int out_size, void* d_ws, size_t ws_size,
                              hipStream_t stream) {
  const float* x      = (const float*)d_in[0];
  const float* w_qkv  = (const float*)d_in[1];
  const float* w_out  = (const float*)d_in[2];
  const float* b_out  = (const float*)d_in[3];
  // d_in[4], d_in[5] (rel_h, rel_w): per-query-row constant bias is softmax-invariant -> unused
  float* res = (float*)d_out;
  unsigned short* wbf = (unsigned short*)d_ws;  // [0,2MB) weights bf16

  convert_weights<<<640, 256, 0, stream>>>(w_qkv, w_out, wbf);

  // 4 parity classes; class (0,0) first with plain stores (covers every output
  // element exactly once -> no memset needed), remaining classes accumulate.
  const int cls[4][5] = {
      {0, 0, 8, 8, 0},  // n even, w even: 512 blocks, store
      {0, 1, 8, 7, 1},  // n even, w odd : 448 blocks, add
      {1, 0, 7, 8, 1},  // n odd,  w even: 448 blocks, add
      {1, 1, 7, 7, 1},  // n odd,  w odd : 392 blocks, add
  };
  for (int c = 0; c < 4; ++c) {
    int nblk = 8 * cls[c][2] * cls[c][3];
    swin_kernel<<<nblk, 512, 0, stream>>>(x, b_out, wbf, wbf + 786432, res,
                                          cls[c][0], cls[c][1], cls[c][2],
                                          cls[c][3], cls[c][4]);
  }
}

// Round 7
// 634.838 us; speedup vs baseline: 2.6309x; 1.0162x over previous
//
#include <hip/hip_runtime.h>

#define NHW 15

typedef __bf16 bf16x8 __attribute__((ext_vector_type(8)));
typedef float f32x4 __attribute__((ext_vector_type(4)));
typedef unsigned short u16x8 __attribute__((ext_vector_type(8)));

__device__ __forceinline__ unsigned short f2bf(float f) {
  unsigned x = __float_as_uint(f);
  unsigned r = ((x >> 16) & 1u) + 0x7fffu;  // round-to-nearest-even
  x += r;
  return (unsigned short)(x >> 16);
}

// 2 f32 -> packed 2xbf16 in one instruction (RNE), replaces ~9 VALU ops.
__device__ __forceinline__ unsigned cvtpk(float lo, float hi) {
  unsigned r;
  asm("v_cvt_pk_bf16_f32 %0, %1, %2" : "=v"(r) : "v"(lo), "v"(hi));
  return r;
}

// K-permutation for GEMM1: stored col c' <-> original channel c = 64*(c'%8) + c'/8.
// Applied to BOTH xv staging and w_qkv columns; dot product is invariant.
// w_qkv: dst[o][a*8+e] = wq[o][64*e + a].  w_out: unpermuted.
__global__ void convert_weights(const float* __restrict__ wq,
                                const float* __restrict__ wo,
                                unsigned short* __restrict__ dst) {
  int t = blockIdx.x * 256 + threadIdx.x;
  if (t < 98304) {  // 1536 * 64
    int o = t >> 6, a = t & 63;
    const float* src = wq + (size_t)o * 512 + a;
    u16x8 v;
    #pragma unroll
    for (int e = 0; e < 8; ++e) v[e] = f2bf(src[e * 64]);
    *(u16x8*)(dst + (size_t)o * 512 + a * 8) = v;
  } else {          // w_out: 512*512 / 4 per thread
    int i = (t - 98304) * 4;
    float4 v = *(const float4*)(wo + i);
    ushort4 o4;
    o4.x = f2bf(v.x); o4.y = f2bf(v.y); o4.z = f2bf(v.z); o4.w = f2bf(v.w);
    *(ushort4*)(dst + 786432 + i) = o4;
  }
}

// __launch_bounds__(512), NO min-waves arg: unified VGPR+AGPR ~160/wave ->
// 8 waves/CU tier (m69). (512,4) spilled 12GB (r2); (512,2) spilled too (r5).
//
// Parity-class launch: windows with fixed (n%2, w%2) never overlap (stride 4,
// kernel 8). 4 sequential launches; class (0,0) covers every output pixel
// exactly once -> plain stores (do_add=0); others load-add-store.
__launch_bounds__(512)
__global__ void swin_kernel(const float* __restrict__ x,
                            const float* __restrict__ b_out,
                            const unsigned short* __restrict__ wq_all,  // [1536][512] bf16, K-permuted
                            const unsigned short* __restrict__ wo,      // [512][512]  bf16
                            float* __restrict__ res,
                            int n0, int w0, int nN, int nW, int do_add) {
  // two regions (1 block/CU, 160KB available):
  //   region xv : xv[64][520] bf16 (66560B); later att_out[64][520]
  //   region sc : 8 x 10240B per-wave attention scratch; later fl[32][517] f32
  __shared__ __align__(16) unsigned short lds_xv[64 * 520];  // 66560 B
  __shared__ __align__(16) unsigned short lds_sc[8 * 5120];  // 81920 B

  const int tid  = threadIdx.x;
  const int wave = tid >> 6;
  const int ln   = tid & 63;
  const int rowa = ln & 15;   // A-frag row / B-frag col within 16-tile
  const int kgrp = ln >> 4;   // 0..3 : k-subgroup (8 elems each)
  const int rbase = kgrp * 4; // C/D-layout row base within 16-tile

  const int bid = blockIdx.x;
  const int b  = bid / (nN * nW);
  const int rm = bid % (nN * nW);
  const int n  = n0 + 2 * (rm / nW);
  const int w  = w0 + 2 * (rm % nW);
  const int i0 = n * 4, j0 = w * 4;

  // ---------------- stage patch xv (bf16, K-permuted) ----------------
  // xv'[l][pos*8+e] = x[b, i0+pos/8, j0+pos%8, 8l+e]
  // Prefetch ALL 16 float4 loads first (one HBM latency), then pack+write.
  {
    const float* src = x + (((size_t)(b * 64 + i0)) * 64 + j0 + wave) * 512 + 8 * ln;
    float4 v0[8], v1[8];
    #pragma unroll
    for (int r = 0; r < 8; ++r) {
      v0[r] = *(const float4*)(src + (size_t)r * 32768);      // row stride 64*512
      v1[r] = *(const float4*)(src + (size_t)r * 32768 + 4);
    }
    #pragma unroll
    for (int r = 0; r < 8; ++r) {
      uint4 pk;
      pk.x = cvtpk(v0[r].x, v0[r].y);
      pk.y = cvtpk(v0[r].z, v0[r].w);
      pk.z = cvtpk(v1[r].x, v1[r].y);
      pk.w = cvtpk(v1[r].z, v1[r].w);
      *(uint4*)(lds_xv + ln * 520 + (r * 8 + wave) * 8) = pk;
    }
  }
  __syncthreads();

  // ---------------- GEMM1: qkv = xv @ W^T (3 steps; wave owns head `wave`) ----
  // 1-deep software pipeline on the global B-frag loads (L2 latency ~200cyc
  // exposed at 2 waves/SIMD otherwise).
  unsigned qp[4][4][2], kp[4][4][2], vp[4][4][2];  // packed bf16 pairs (rows 2p,2p+1)
  {
    auto step = [&](int O, unsigned (&dst)[4][4][2]) {
      f32x4 acc[4][4];
      #pragma unroll
      for (int i = 0; i < 4; ++i)
        #pragma unroll
        for (int j = 0; j < 4; ++j) acc[i][j] = (f32x4){0.f, 0.f, 0.f, 0.f};
      const unsigned short* wb = wq_all + (size_t)O * 512 + (size_t)rowa * 512 + kgrp * 8;
      bf16x8 bfr[4];
      #pragma unroll
      for (int nt = 0; nt < 4; ++nt)
        bfr[nt] = *(const bf16x8*)(wb + (size_t)nt * 8192);  // ks=0
      #pragma unroll 2
      for (int ks = 0; ks < 16; ++ks) {
        bf16x8 bn[4];
        if (ks < 15) {
          #pragma unroll
          for (int nt = 0; nt < 4; ++nt)
            bn[nt] = *(const bf16x8*)(wb + (size_t)nt * 8192 + (ks + 1) * 32);
        }
        bf16x8 a[4];
        #pragma unroll
        for (int mt = 0; mt < 4; ++mt)
          a[mt] = *(const bf16x8*)(lds_xv + (mt * 16 + rowa) * 520 + ks * 32 + kgrp * 8);
        #pragma unroll
        for (int nt = 0; nt < 4; ++nt)
          #pragma unroll
          for (int mt = 0; mt < 4; ++mt)
            acc[mt][nt] = __builtin_amdgcn_mfma_f32_16x16x32_bf16(a[mt], bfr[nt], acc[mt][nt], 0, 0, 0);
        if (ks < 15) {
          #pragma unroll
          for (int nt = 0; nt < 4; ++nt) bfr[nt] = bn[nt];
        }
      }
      #pragma unroll
      for (int mt = 0; mt < 4; ++mt)
        #pragma unroll
        for (int nt = 0; nt < 4; ++nt)
          #pragma unroll
          for (int p = 0; p < 2; ++p)
            dst[mt][nt][p] = cvtpk(acc[mt][nt][2 * p], acc[mt][nt][2 * p + 1]);
    };
    step(wave * 64,        qp);
    step(512 + wave * 64,  kp);
    step(1024 + wave * 64, vp);
  }
  // no barrier: attention scratch is a separate LDS region, wave-private.

  // ---------------- attention: head = wave, all private -------------
  unsigned short* qsc = lds_sc + wave * 5120;  // 64 x 40 bf16 rows (80B, 16B aligned)
  unsigned short* ksc = qsc + 2560;

  f32x4 dt_[4][4];
  #pragma unroll
  for (int i = 0; i < 4; ++i)
    #pragma unroll
    for (int j = 0; j < 4; ++j) dt_[i][j] = (f32x4){0.f, 0.f, 0.f, 0.f};

  #pragma unroll
  for (int h2 = 0; h2 < 2; ++h2) {  // d-half of K=64
    #pragma unroll
    for (int mt = 0; mt < 4; ++mt)
      #pragma unroll
      for (int cc = 0; cc < 2; ++cc) {
        int ct = 2 * h2 + cc;
        #pragma unroll
        for (int p = 0; p < 2; ++p) {
          unsigned uq = qp[mt][ct][p];
          unsigned uk = kp[mt][ct][p];
          int rr = mt * 16 + rbase + 2 * p;
          int dd = cc * 16 + rowa;
          qsc[rr * 40 + dd]       = (unsigned short)uq;
          qsc[(rr + 1) * 40 + dd] = (unsigned short)(uq >> 16);
          ksc[rr * 40 + dd]       = (unsigned short)uk;
          ksc[(rr + 1) * 40 + dd] = (unsigned short)(uk >> 16);
        }
      }
    bf16x8 aq[4];
    #pragma unroll
    for (int mt = 0; mt < 4; ++mt)
      aq[mt] = *(const bf16x8*)(qsc + (mt * 16 + rowa) * 40 + kgrp * 8);
    #pragma unroll
    for (int nt = 0; nt < 4; ++nt) {
      bf16x8 bk = *(const bf16x8*)(ksc + (nt * 16 + rowa) * 40 + kgrp * 8);
      #pragma unroll
      for (int mt = 0; mt < 4; ++mt)
        dt_[mt][nt] = __builtin_amdgcn_mfma_f32_16x16x32_bf16(aq[mt], bk, dt_[mt][nt], 0, 0, 0);
    }
  }

  // softmax (scale = hd^-0.5 = 1/8); per-row constant bias drops out exactly
  const float SC = 0.125f * 1.44269504088896f;
  float rsum[4][4];
  #pragma unroll
  for (int mt = 0; mt < 4; ++mt)
    #pragma unroll
    for (int j = 0; j < 4; ++j) {
      float m = dt_[mt][0][j];
      #pragma unroll
      for (int nt = 1; nt < 4; ++nt) m = fmaxf(m, dt_[mt][nt][j]);
      #pragma unroll
      for (int s = 1; s < 16; s <<= 1) m = fmaxf(m, __shfl_xor(m, s, 64));
      float sum = 0.f;
      #pragma unroll
      for (int nt = 0; nt < 4; ++nt) {
        float p = exp2f((dt_[mt][nt][j] - m) * SC);
        dt_[mt][nt][j] = p;
        sum += p;
      }
      #pragma unroll
      for (int s = 1; s < 16; s <<= 1) sum += __shfl_xor(sum, s, 64);
      rsum[mt][j] = sum;
    }

  // PV: out_h = P @ v  (stage P and v^T per m-half; same-wave scratch reuse)
  unsigned short* Psc  = qsc;
  unsigned short* vTsc = ksc;
  f32x4 oat[4][4];
  #pragma unroll
  for (int i = 0; i < 4; ++i)
    #pragma unroll
    for (int j = 0; j < 4; ++j) oat[i][j] = (f32x4){0.f, 0.f, 0.f, 0.f};

  #pragma unroll
  for (int mh = 0; mh < 2; ++mh) {
    #pragma unroll
    for (int mt = 0; mt < 4; ++mt)
      #pragma unroll
      for (int cc = 0; cc < 2; ++cc) {
        int ct = 2 * mh + cc;
        #pragma unroll
        for (int j = 0; j < 4; ++j)
          Psc[(mt * 16 + rbase + j) * 40 + cc * 16 + rowa] = f2bf(dt_[mt][ct][j]);
      }
    #pragma unroll
    for (int mm = 0; mm < 2; ++mm) {
      int mtm = 2 * mh + mm;
      #pragma unroll
      for (int ct = 0; ct < 4; ++ct)
        #pragma unroll
        for (int p = 0; p < 2; ++p) {
          unsigned u = vp[mtm][ct][p];
          int m_ = mm * 16 + rbase + 2 * p;
          int d  = ct * 16 + rowa;
          *(unsigned*)(vTsc + d * 40 + m_) = u;  // two adjacent m' -> one b32 write
        }
    }
    bf16x8 ap[4];
    #pragma unroll
    for (int mt = 0; mt < 4; ++mt)
      ap[mt] = *(const bf16x8*)(Psc + (mt * 16 + rowa) * 40 + kgrp * 8);
    #pragma unroll
    for (int dtt = 0; dtt < 4; ++dtt) {
      bf16x8 bv = *(const bf16x8*)(vTsc + (dtt * 16 + rowa) * 40 + kgrp * 8);
      #pragma unroll
      for (int mt = 0; mt < 4; ++mt)
        oat[mt][dtt] = __builtin_amdgcn_mfma_f32_16x16x32_bf16(ap[mt], bv, oat[mt][dtt], 0, 0, 0);
    }
  }

  __syncthreads();  // all waves done with GEMM1's xv reads before att_out overlay

  // normalize + stage att_out (cols [wave*64, wave*64+64)) into lds_xv
  #pragma unroll
  for (int mt = 0; mt < 4; ++mt)
    #pragma unroll
    for (int j = 0; j < 4; ++j) {
      float inv = 1.f / rsum[mt][j];
      #pragma unroll
      for (int dtt = 0; dtt < 4; ++dtt)
        lds_xv[(mt * 16 + rbase + j) * 520 + wave * 64 + dtt * 16 + rowa] =
            f2bf(oat[mt][dtt][j] * inv);
    }
  __syncthreads();

  // ---------------- GEMM2: out2 = att_out @ w_out^T + b_out ----------
  f32x4 a2[4][4];
  #pragma unroll
  for (int i = 0; i < 4; ++i)
    #pragma unroll
    for (int j = 0; j < 4; ++j) a2[i][j] = (f32x4){0.f, 0.f, 0.f, 0.f};
  {
    const unsigned short* wb = wo + (size_t)(wave * 64 + rowa) * 512 + kgrp * 8;
    bf16x8 bw[4];
    #pragma unroll
    for (int nt = 0; nt < 4; ++nt)
      bw[nt] = *(const bf16x8*)(wb + (size_t)nt * 8192);  // ks=0
    #pragma unroll 2
    for (int ks = 0; ks < 16; ++ks) {
      bf16x8 bn[4];
      if (ks < 15) {
        #pragma unroll
        for (int nt = 0; nt < 4; ++nt)
          bn[nt] = *(const bf16x8*)(wb + (size_t)nt * 8192 + (ks + 1) * 32);
      }
      bf16x8 a[4];
      #pragma unroll
      for (int mt = 0; mt < 4; ++mt)
        a[mt] = *(const bf16x8*)(lds_xv + (mt * 16 + rowa) * 520 + ks * 32 + kgrp * 8);
      #pragma unroll
      for (int nt = 0; nt < 4; ++nt)
        #pragma unroll
        for (int mt = 0; mt < 4; ++mt)
          a2[mt][nt] = __builtin_amdgcn_mfma_f32_16x16x32_bf16(a[mt], bw[nt], a2[mt][nt], 0, 0, 0);
      if (ks < 15) {
        #pragma unroll
        for (int nt = 0; nt < 4; ++nt) bw[nt] = bn[nt];
      }
    }
  }

  float bias[4];
  #pragma unroll
  for (int nt = 0; nt < 4; ++nt) bias[nt] = b_out[wave * 64 + nt * 16 + rowa];

  // ---------------- epilogue: LDS un-scramble + NON-ATOMIC write ----
  // value (l = mt*16+kgrp*4+j, o = wave*64+nt*16+rowa):
  //   pixel p = nt*16+rowa, channel ch = l*8 + wave.
  // Phase ph covers p in [32ph, 32ph+32): stage fl[p-32ph][ch] f32 (stride 517)
  // in the (dead) scratch region, then wave-contiguous 1KB reads ->
  // float4 store (or load-add-store).
  float* fl = (float*)lds_sc;  // [32][517] f32 = 66176 B
  #pragma unroll
  for (int ph = 0; ph < 2; ++ph) {
    if (ph) __syncthreads();  // phase-0 reads done before rewrite
    #pragma unroll
    for (int nt2 = 0; nt2 < 2; ++nt2) {
      int nt = 2 * ph + nt2;
      int prow = nt2 * 16 + rowa;
      #pragma unroll
      for (int mt = 0; mt < 4; ++mt)
        #pragma unroll
        for (int j = 0; j < 4; ++j) {
          int ch = (mt * 16 + rbase + j) * 8 + wave;
          fl[prow * 517 + ch] = a2[mt][nt][j] + bias[nt];
        }
    }
    __syncthreads();
    #pragma unroll
    for (int it = 0; it < 8; ++it) {
      int idx = it * 512 + tid;        // float4 index in [0,4096)
      int pp  = idx >> 7;              // local pixel 0..31
      int c4  = (idx & 127) << 2;      // channel 0..508
      float4 v = *(const float4*)(fl + pp * 517 + c4);
      int p  = ph * 32 + pp;
      int gh = i0 + (p >> 3), gw = j0 + (p & 7);
      float* dst = res + (((size_t)(b * 64 + gh)) * 64 + gw) * 512 + c4;
      if (do_add) {
        float4 old = *(const float4*)dst;
        v.x += old.x; v.y += old.y; v.z += old.z; v.w += old.w;
      }
      *(float4*)dst = v;
    }
  }
}

extern "C" void kernel_launch(void* const* d_in, const int* in_sizes, int n_in,
                              void* d_out, int out_size, void* d_ws, size_t ws_size,
                              hipStream_t stream) {
  const float* x      = (const float*)d_in[0];
  const float* w_qkv  = (const float*)d_in[1];
  const float* w_out  = (const float*)d_in[2];
  const float* b_out  = (const float*)d_in[3];
  // d_in[4], d_in[5] (rel_h, rel_w): per-query-row constant bias is softmax-invariant -> unused
  float* res = (float*)d_out;
  unsigned short* wbf = (unsigned short*)d_ws;  // [0,2MB) weights bf16

  convert_weights<<<640, 256, 0, stream>>>(w_qkv, w_out, wbf);

  // 4 parity classes; class (0,0) first with plain stores (covers every output
  // element exactly once -> no memset needed), remaining classes accumulate.
  const int cls[4][5] = {
      {0, 0, 8, 8, 0},  // n even, w even: 512 blocks, store
      {0, 1, 8, 7, 1},  // n even, w odd : 448 blocks, add
      {1, 0, 7, 8, 1},  // n odd,  w even: 448 blocks, add
      {1, 1, 7, 7, 1},  // n odd,  w odd : 392 blocks, add
  };
  for (int c = 0; c < 4; ++c) {
    int nblk = 8 * cls[c][2] * cls[c][3];
    swin_kernel<<<nblk, 512, 0, stream>>>(x, b_out, wbf, wbf + 786432, res,
                                          cls[c][0], cls[c][1], cls[c][2],
                                          cls[c][3], cls[c][4]);
  }
}